// Round 6
// baseline (2552.154 us; speedup 1.0000x reference)
//
#include <hip/hip_runtime.h>

#define QD 8
#define BLK 256

typedef unsigned short u16;
typedef unsigned int   u32;

__device__ __forceinline__ float bf2f(u16 u) {
    return __uint_as_float(((u32)u) << 16);
}
__device__ __forceinline__ u16 f2bf(float f) {   // RNE; inputs are finite probabilities
    u32 x = __float_as_uint(f);
    return (u16)((x + 0x7FFFu + ((x >> 16) & 1u)) >> 16);
}

__device__ __forceinline__ void load8(const float* __restrict__ p, float v[QD]) {
    const float4* p4 = reinterpret_cast<const float4*>(p);
    float4 a = p4[0], b = p4[1];
    v[0]=a.x; v[1]=a.y; v[2]=a.z; v[3]=a.w;
    v[4]=b.x; v[5]=b.y; v[6]=b.z; v[7]=b.w;
}
__device__ __forceinline__ void store8(float* __restrict__ p, const float v[QD]) {
    float4* p4 = reinterpret_cast<float4*>(p);
    float4 a = {v[0],v[1],v[2],v[3]};
    float4 b = {v[4],v[5],v[6],v[7]};
    p4[0]=a; p4[1]=b;
}
__device__ __forceinline__ void loadbf8(const u16* __restrict__ p, float v[QD]) {
    uint4 u = *reinterpret_cast<const uint4*>(p);
    v[0]=bf2f(u.x & 0xffff); v[1]=bf2f(u.x >> 16);
    v[2]=bf2f(u.y & 0xffff); v[3]=bf2f(u.y >> 16);
    v[4]=bf2f(u.z & 0xffff); v[5]=bf2f(u.z >> 16);
    v[6]=bf2f(u.w & 0xffff); v[7]=bf2f(u.w >> 16);
}
__device__ __forceinline__ void storebf8(u16* __restrict__ p, const float v[QD]) {
    uint4 u;
    u.x = (u32)f2bf(v[0]) | ((u32)f2bf(v[1]) << 16);
    u.y = (u32)f2bf(v[2]) | ((u32)f2bf(v[3]) << 16);
    u.z = (u32)f2bf(v[4]) | ((u32)f2bf(v[5]) << 16);
    u.w = (u32)f2bf(v[6]) | ((u32)f2bf(v[7]) << 16);
    *reinterpret_cast<uint4*>(p) = u;
}

__device__ __forceinline__ void softmax8(const float v[QD], float o[QD]) {
    float m = v[0];
    #pragma unroll
    for (int i=1;i<QD;i++) m = fmaxf(m, v[i]);
    float s = 0.f;
    #pragma unroll
    for (int i=0;i<QD;i++){ o[i] = expf(v[i]-m); s += o[i]; }
    float inv = 1.0f/s;
    #pragma unroll
    for (int i=0;i<QD;i++) o[i] *= inv;
}

// deg[ei[x]]++ over flat (2,E): multiset of dst over all directed edges == all ei entries
__global__ void count_kernel(const int* __restrict__ ei, int* __restrict__ deg, int twoE) {
    int x = blockIdx.x*BLK + threadIdx.x;
    if (x >= twoE) return;
    atomicAdd(&deg[ei[x]], 1);
}

// single-block exclusive scan: deg -> rowstart (N+1), cursor = rowstart
__global__ void scan_kernel(const int* __restrict__ deg, int* __restrict__ rowstart,
                            int* __restrict__ cursor, int N, int twoE) {
    __shared__ int part[1024];
    int tid = threadIdx.x;
    int chunk = (N + 1023) / 1024;
    int lo = tid * chunk;
    int hi = lo + chunk; if (hi > N) hi = N; if (lo > N) lo = N;
    int s = 0;
    for (int i = lo; i < hi; ++i) s += deg[i];
    part[tid] = s;
    __syncthreads();
    for (int off = 1; off < 1024; off <<= 1) {
        int v = (tid >= off) ? part[tid - off] : 0;
        __syncthreads();
        part[tid] += v;
        __syncthreads();
    }
    int run = (tid == 0) ? 0 : part[tid - 1];
    for (int i = lo; i < hi; ++i) {
        rowstart[i] = run; cursor[i] = run; run += deg[i];
    }
    if (tid == 1023) rowstart[N] = twoE;
}

// per edge e: slot grouped by dst[e]; adj/slotOf; fused init P[slot] = bf16(softmax(psi0[e]))
__global__ void fill_kernel(const int* __restrict__ ei, const float* __restrict__ psi0,
                            int* __restrict__ cursor, int* __restrict__ adj,
                            int* __restrict__ slotOf, u16* __restrict__ P,
                            int E, int twoE) {
    int e = blockIdx.x*BLK + threadIdx.x;
    if (e >= twoE) return;
    int r = (e < E) ? (e + E) : (e - E);
    int d = ei[r];                       // dst[e]
    int slot = atomicAdd(&cursor[d], 1);
    adj[slot] = e;
    slotOf[e] = slot;
    float v[QD], o[QD];
    load8(psi0 + (size_t)e*QD, v);
    softmax8(v, o);
    storebf8(P + (size_t)slot*QD, o);
}

// rn[slotOf[e]] = (revslot, owner node) = (slotOf[rev e], ei[rev e])
__global__ void aux_kernel(const int* __restrict__ ei, const int* __restrict__ slotOf,
                           int2* __restrict__ rn, int E, int twoE) {
    int e = blockIdx.x*BLK + threadIdx.x;
    if (e >= twoE) return;
    int r = (e < E) ? (e + E) : (e - E);
    rn[slotOf[e]] = make_int2(slotOf[r], ei[r]);
}

// A: 8 lanes per node, contiguous segment read of permuted bf16 P.
// ns[n][q] = sum log1p(w*P[i][q]); fused h: 8-lane softmax + wave reduce + atomic.
__global__ void nodesumA(const u16* __restrict__ P, const int* __restrict__ rowstart,
                         float* __restrict__ ns, float* __restrict__ hslot,
                         const float* __restrict__ beta, int N) {
    int gid = blockIdx.x*BLK + threadIdx.x;
    int node = gid >> 3;
    int q = gid & 7;
    float w = expf(beta[0]) - 1.0f;
    float hc = 0.0f;
    if (node < N) {
        int s = rowstart[node], t = rowstart[node + 1];
        float acc = 0.0f;
        for (int i = s; i < t; ++i)
            acc += log1pf(w * bf2f(P[(size_t)i*QD + q]));
        ns[(size_t)node*QD + q] = acc;
        float m = acc;
        #pragma unroll
        for (int d = 1; d < 8; d <<= 1) m = fmaxf(m, __shfl_xor(m, d, 8));
        float ex = expf(acc - m);
        float ss = ex;
        #pragma unroll
        for (int d = 1; d < 8; d <<= 1) ss += __shfl_xor(ss, d, 8);
        hc = ex / ss;            // marginal[node][q]
    }
    hc += __shfl_xor(hc, 8);
    hc += __shfl_xor(hc, 16);
    hc += __shfl_xor(hc, 32);
    if ((threadIdx.x & 63) < 8) unsafeAtomicAdd(&hslot[threadIdx.x & 7], hc);
}

// In-place pair update in slot space. rev is a fixed-point-free involution on slots,
// so thread owning pair (i, j=rn[i].x), i<j, exclusively writes both:
//   new_P[i] = softmax( ns[rn[j].y] - log1p(w*P[j]) - h )
//   new_P[j] = softmax( ns[rn[i].y] - log1p(w*P[i]) - h )
// LAST: also scatter f32 rows to d_out at edge ids adj[i], adj[j].
template<bool LAST>
__global__ void pair_update(u16* __restrict__ P, const int2* __restrict__ rn,
                            const float* __restrict__ ns, const float* __restrict__ hslot,
                            const int* __restrict__ adj, float* __restrict__ out,
                            const float* __restrict__ beta, int twoE, float invN) {
    int i = blockIdx.x*BLK + threadIdx.x;
    if (i >= twoE) return;
    int2 a = rn[i];
    int j = a.x;
    if (j < i) return;                   // pair handled by the lower slot
    int ni = a.y;
    int nj = rn[j].y;
    float b = beta[0];
    float w = expf(b) - 1.0f;
    float hb = b * invN;
    float pi[QD], pj[QD], nsi[QD], nsj[QD], lg[QD], oi[QD], oj[QD], h8[QD];
    loadbf8(P + (size_t)i*QD, pi);
    loadbf8(P + (size_t)j*QD, pj);
    load8(ns + (size_t)ni*QD, nsi);
    load8(ns + (size_t)nj*QD, nsj);
    #pragma unroll
    for (int q = 0; q < QD; q++) h8[q] = hb * hslot[q];
    #pragma unroll
    for (int q = 0; q < QD; q++) lg[q] = nsj[q] - log1pf(w*pj[q]) - h8[q];
    softmax8(lg, oi);
    #pragma unroll
    for (int q = 0; q < QD; q++) lg[q] = nsi[q] - log1pf(w*pi[q]) - h8[q];
    softmax8(lg, oj);
    storebf8(P + (size_t)i*QD, oi);
    storebf8(P + (size_t)j*QD, oj);
    if (LAST) {
        store8(out + (size_t)adj[i]*QD, oi);
        store8(out + (size_t)adj[j]*QD, oj);
    }
}

// marginal = softmax(ns) row-wise -> out tail (f32)
__global__ void marginal_kernel(const float* __restrict__ ns, float* __restrict__ out, int N) {
    int n = blockIdx.x*BLK + threadIdx.x;
    if (n >= N) return;
    float v[QD], o[QD];
    load8(ns + (size_t)n*QD, v);
    softmax8(v, o);
    store8(out + (size_t)n*QD, o);
}

extern "C" void kernel_launch(void* const* d_in, const int* in_sizes, int n_in,
                              void* d_out, int out_size, void* d_ws, size_t ws_size,
                              hipStream_t stream) {
    const int*   ei   = (const int*)d_in[0];    // (2,E) flat: [0..E)=src_u, [E..2E)=dst_u
    const float* psi0 = (const float*)d_in[1];  // (2E, Q)
    const float* beta = (const float*)d_in[2];  // (1,)

    int twoE = in_sizes[0];
    int E    = twoE / 2;
    int N    = (out_size - in_sizes[1]) / QD;

    // workspace layout (256B-aligned); total ~53.4 MB (<= proven 54.4 MB bound)
    char* w = (char*)d_ws;
    size_t o = 0;
    auto al = [](size_t x){ return (x + 255) & ~(size_t)255; };
    u16*  P      = (u16*)(w + o);   o = al(o + (size_t)twoE*QD*2);  // 25.6 MB
    int2* rn     = (int2*)(w + o);  o = al(o + (size_t)twoE*8);     // 12.8 MB
    int*  slotOf = (int*)(w + o);   o = al(o + (size_t)twoE*4);     //  6.4 MB
    int*  adj    = (int*)(w + o);   o = al(o + (size_t)twoE*4);     //  6.4 MB
    float* ns    = (float*)(w + o); o = al(o + (size_t)N*QD*4);     //  1.6 MB
    int*  deg    = (int*)(w + o);   o = al(o + (size_t)N*4);
    int*  rowstart=(int*)(w + o);   o = al(o + ((size_t)N+1)*4);
    int*  cursor = (int*)(w + o);   o = al(o + (size_t)N*4);
    float* hsl   = (float*)(w + o);                                  // 11*8 floats

    int eg2 = (twoE + BLK - 1) / BLK;
    int ng8 = (N*QD + BLK - 1) / BLK;
    int ng  = (N    + BLK - 1) / BLK;
    float invN = 1.0f / (float)N;
    float* out = (float*)d_out;

    hipMemsetAsync(deg, 0, (size_t)N * sizeof(int), stream);
    hipMemsetAsync(hsl, 0, (size_t)11 * QD * sizeof(float), stream);

    count_kernel<<<eg2, BLK, 0, stream>>>(ei, deg, twoE);
    scan_kernel<<<1, 1024, 0, stream>>>(deg, rowstart, cursor, N, twoE);
    fill_kernel<<<eg2, BLK, 0, stream>>>(ei, psi0, cursor, adj, slotOf, P, E, twoE);
    aux_kernel<<<eg2, BLK, 0, stream>>>(ei, slotOf, rn, E, twoE);

    for (int k = 0; k < 10; ++k) {
        nodesumA<<<ng8, BLK, 0, stream>>>(P, rowstart, ns, hsl + k*QD, beta, N);
        if (k < 9)
            pair_update<false><<<eg2, BLK, 0, stream>>>(P, rn, ns, hsl + k*QD,
                                                        adj, out, beta, twoE, invN);
        else
            pair_update<true><<<eg2, BLK, 0, stream>>>(P, rn, ns, hsl + k*QD,
                                                       adj, out, beta, twoE, invN);
    }
    // final node field from final P (bf16) -> marginal tail; psi already in d_out (f32)
    nodesumA<<<ng8, BLK, 0, stream>>>(P, rowstart, ns, hsl + 10*QD, beta, N);
    marginal_kernel<<<ng, BLK, 0, stream>>>(ns, out + (size_t)twoE*QD, N);
}

// Round 7
// 2210.058 us; speedup vs baseline: 1.1548x; 1.1548x over previous
//
#include <hip/hip_runtime.h>

#define QD 8
#define BLK 256

typedef unsigned short u16;
typedef unsigned int   u32;

__device__ __forceinline__ float bf2f(u16 u) {
    return __uint_as_float(((u32)u) << 16);
}
__device__ __forceinline__ u16 f2bf(float f) {   // RNE; inputs are finite probabilities
    u32 x = __float_as_uint(f);
    return (u16)((x + 0x7FFFu + ((x >> 16) & 1u)) >> 16);
}

__device__ __forceinline__ void load8(const float* __restrict__ p, float v[QD]) {
    const float4* p4 = reinterpret_cast<const float4*>(p);
    float4 a = p4[0], b = p4[1];
    v[0]=a.x; v[1]=a.y; v[2]=a.z; v[3]=a.w;
    v[4]=b.x; v[5]=b.y; v[6]=b.z; v[7]=b.w;
}
__device__ __forceinline__ void store8(float* __restrict__ p, const float v[QD]) {
    float4* p4 = reinterpret_cast<float4*>(p);
    float4 a = {v[0],v[1],v[2],v[3]};
    float4 b = {v[4],v[5],v[6],v[7]};
    p4[0]=a; p4[1]=b;
}
__device__ __forceinline__ void loadbf8(const u16* __restrict__ p, float v[QD]) {
    uint4 u = *reinterpret_cast<const uint4*>(p);
    v[0]=bf2f(u.x & 0xffff); v[1]=bf2f(u.x >> 16);
    v[2]=bf2f(u.y & 0xffff); v[3]=bf2f(u.y >> 16);
    v[4]=bf2f(u.z & 0xffff); v[5]=bf2f(u.z >> 16);
    v[6]=bf2f(u.w & 0xffff); v[7]=bf2f(u.w >> 16);
}
__device__ __forceinline__ void storebf8(u16* __restrict__ p, const float v[QD]) {
    uint4 u;
    u.x = (u32)f2bf(v[0]) | ((u32)f2bf(v[1]) << 16);
    u.y = (u32)f2bf(v[2]) | ((u32)f2bf(v[3]) << 16);
    u.z = (u32)f2bf(v[4]) | ((u32)f2bf(v[5]) << 16);
    u.w = (u32)f2bf(v[6]) | ((u32)f2bf(v[7]) << 16);
    *reinterpret_cast<uint4*>(p) = u;
}

__device__ __forceinline__ void softmax8(const float v[QD], float o[QD]) {
    float m = v[0];
    #pragma unroll
    for (int i=1;i<QD;i++) m = fmaxf(m, v[i]);
    float s = 0.f;
    #pragma unroll
    for (int i=0;i<QD;i++){ o[i] = expf(v[i]-m); s += o[i]; }
    float inv = 1.0f/s;
    #pragma unroll
    for (int i=0;i<QD;i++) o[i] *= inv;
}

// deg[ei[x]]++ over flat (2,E): multiset of dst over all directed edges == all ei entries
__global__ void count_kernel(const int* __restrict__ ei, int* __restrict__ deg, int twoE) {
    int x = blockIdx.x*BLK + threadIdx.x;
    if (x >= twoE) return;
    atomicAdd(&deg[ei[x]], 1);
}

// single-block exclusive scan: deg -> rowstart (N+1), cursor = rowstart
__global__ void scan_kernel(const int* __restrict__ deg, int* __restrict__ rowstart,
                            int* __restrict__ cursor, int N, int twoE) {
    __shared__ int part[1024];
    int tid = threadIdx.x;
    int chunk = (N + 1023) / 1024;
    int lo = tid * chunk;
    int hi = lo + chunk; if (hi > N) hi = N; if (lo > N) lo = N;
    int s = 0;
    for (int i = lo; i < hi; ++i) s += deg[i];
    part[tid] = s;
    __syncthreads();
    for (int off = 1; off < 1024; off <<= 1) {
        int v = (tid >= off) ? part[tid - off] : 0;
        __syncthreads();
        part[tid] += v;
        __syncthreads();
    }
    int run = (tid == 0) ? 0 : part[tid - 1];
    for (int i = lo; i < hi; ++i) {
        rowstart[i] = run; cursor[i] = run; run += deg[i];
    }
    if (tid == 1023) rowstart[N] = twoE;
}

// adj[slot] = e, slot grouped by dst[e] = ei[rev(e)]
__global__ void fill_kernel(const int* __restrict__ ei, int* __restrict__ cursor,
                            int* __restrict__ adj, int E, int twoE) {
    int e = blockIdx.x*BLK + threadIdx.x;
    if (e >= twoE) return;
    int r = (e < E) ? (e + E) : (e - E);
    int d = ei[r];
    int slot = atomicAdd(&cursor[d], 1);
    adj[slot] = e;
}

// psi_bf[e] = bf16(softmax(psi0[e])), contiguous
__global__ void init_kernel(const float* __restrict__ psi0, u16* __restrict__ psi, int twoE) {
    int e = blockIdx.x*BLK + threadIdx.x;
    if (e >= twoE) return;
    float v[QD], o[QD];
    load8(psi0 + (size_t)e*QD, v);
    softmax8(v, o);
    storebf8(psi + (size_t)e*QD, o);
}

// 8 lanes per node: ns[n][q] = sum over incoming edges of log1p(w*psi[adj[i]][q]).
// Fused h: 8-lane softmax -> marginal; wave-reduce same-q lanes -> 8 atomics/wave.
__global__ void nodesumA(const u16* __restrict__ psi, const int* __restrict__ adj,
                         const int* __restrict__ rowstart,
                         float* __restrict__ ns, float* __restrict__ hslot,
                         const float* __restrict__ beta, int N) {
    int gid = blockIdx.x*BLK + threadIdx.x;
    int node = gid >> 3;
    int q = gid & 7;
    float w = expf(beta[0]) - 1.0f;
    float hc = 0.0f;
    if (node < N) {
        int s = rowstart[node], t = rowstart[node + 1];
        float acc = 0.0f;
        for (int i = s; i < t; ++i) {
            int e = adj[i];
            acc += log1pf(w * bf2f(psi[(size_t)e*QD + q]));
        }
        ns[(size_t)node*QD + q] = acc;
        float m = acc;
        #pragma unroll
        for (int d = 1; d < 8; d <<= 1) m = fmaxf(m, __shfl_xor(m, d, 8));
        float ex = expf(acc - m);
        float ss = ex;
        #pragma unroll
        for (int d = 1; d < 8; d <<= 1) ss += __shfl_xor(ss, d, 8);
        hc = ex / ss;            // marginal[node][q]
    }
    hc += __shfl_xor(hc, 8);
    hc += __shfl_xor(hc, 16);
    hc += __shfl_xor(hc, 32);
    if ((threadIdx.x & 63) < 8) unsafeAtomicAdd(&hslot[threadIdx.x & 7], hc);
}

// In-place pair update in EDGE space: edges t and t+E are mutual reverses.
// Thread t reads both rows contiguously, gathers ns (L2-resident), writes both in place.
//   psi[t]   = softmax( ns[ei[t]]   - log1p(w*psi[t+E]) - h )
//   psi[t+E] = softmax( ns[ei[t+E]] - log1p(w*psi[t])   - h )
// LAST: also write f32 rows to d_out (contiguous — edge order IS output order).
template<bool LAST>
__global__ void pair_update(u16* __restrict__ psi, const int* __restrict__ ei,
                            const float* __restrict__ ns, const float* __restrict__ hslot,
                            float* __restrict__ out, const float* __restrict__ beta,
                            int E, float invN) {
    int t = blockIdx.x*BLK + threadIdx.x;
    if (t >= E) return;
    float b = beta[0];
    float w = expf(b) - 1.0f;
    float hb = b * invN;
    int u = ei[t];          // src of edge t == dst of edge t+E
    int v = ei[t + E];      // dst of edge t == src of edge t+E
    float pf[QD], pr[QD], nsu[QD], nsv[QD], lg[QD], of_[QD], or_[QD], h8[QD];
    loadbf8(psi + (size_t)t*QD, pf);
    loadbf8(psi + ((size_t)t + E)*QD, pr);
    load8(ns + (size_t)u*QD, nsu);
    load8(ns + (size_t)v*QD, nsv);
    #pragma unroll
    for (int q = 0; q < QD; q++) h8[q] = hb * hslot[q];
    #pragma unroll
    for (int q = 0; q < QD; q++) lg[q] = nsu[q] - log1pf(w*pr[q]) - h8[q];
    softmax8(lg, of_);
    #pragma unroll
    for (int q = 0; q < QD; q++) lg[q] = nsv[q] - log1pf(w*pf[q]) - h8[q];
    softmax8(lg, or_);
    storebf8(psi + (size_t)t*QD, of_);
    storebf8(psi + ((size_t)t + E)*QD, or_);
    if (LAST) {
        store8(out + (size_t)t*QD, of_);
        store8(out + ((size_t)t + E)*QD, or_);
    }
}

// marginal = softmax(ns) row-wise -> out tail (f32)
__global__ void marginal_kernel(const float* __restrict__ ns, float* __restrict__ out, int N) {
    int n = blockIdx.x*BLK + threadIdx.x;
    if (n >= N) return;
    float v[QD], o[QD];
    load8(ns + (size_t)n*QD, v);
    softmax8(v, o);
    store8(out + (size_t)n*QD, o);
}

extern "C" void kernel_launch(void* const* d_in, const int* in_sizes, int n_in,
                              void* d_out, int out_size, void* d_ws, size_t ws_size,
                              hipStream_t stream) {
    const int*   ei   = (const int*)d_in[0];    // (2,E) flat: [0..E)=src_u, [E..2E)=dst_u
    const float* psi0 = (const float*)d_in[1];  // (2E, Q)
    const float* beta = (const float*)d_in[2];  // (1,)

    int twoE = in_sizes[0];
    int E    = twoE / 2;
    int N    = (out_size - in_sizes[1]) / QD;

    // workspace layout (256B-aligned); total ~34.3 MB
    char* w = (char*)d_ws;
    size_t o = 0;
    auto al = [](size_t x){ return (x + 255) & ~(size_t)255; };
    u16*  psi    = (u16*)(w + o);   o = al(o + (size_t)twoE*QD*2);  // 25.6 MB
    int*  adj    = (int*)(w + o);   o = al(o + (size_t)twoE*4);     //  6.4 MB
    float* ns    = (float*)(w + o); o = al(o + (size_t)N*QD*4);     //  1.6 MB
    int*  deg    = (int*)(w + o);   o = al(o + (size_t)N*4);
    int*  rowstart=(int*)(w + o);   o = al(o + ((size_t)N+1)*4);
    int*  cursor = (int*)(w + o);   o = al(o + (size_t)N*4);
    float* hsl   = (float*)(w + o);                                  // 11*8 floats

    int eg2 = (twoE + BLK - 1) / BLK;
    int eg1 = (E    + BLK - 1) / BLK;
    int ng8 = (N*QD + BLK - 1) / BLK;
    int ng  = (N    + BLK - 1) / BLK;
    float invN = 1.0f / (float)N;
    float* out = (float*)d_out;

    hipMemsetAsync(deg, 0, (size_t)N * sizeof(int), stream);
    hipMemsetAsync(hsl, 0, (size_t)11 * QD * sizeof(float), stream);

    count_kernel<<<eg2, BLK, 0, stream>>>(ei, deg, twoE);
    scan_kernel<<<1, 1024, 0, stream>>>(deg, rowstart, cursor, N, twoE);
    fill_kernel<<<eg2, BLK, 0, stream>>>(ei, cursor, adj, E, twoE);
    init_kernel<<<eg2, BLK, 0, stream>>>(psi0, psi, twoE);

    for (int k = 0; k < 10; ++k) {
        nodesumA<<<ng8, BLK, 0, stream>>>(psi, adj, rowstart, ns, hsl + k*QD, beta, N);
        if (k < 9)
            pair_update<false><<<eg1, BLK, 0, stream>>>(psi, ei, ns, hsl + k*QD,
                                                        out, beta, E, invN);
        else
            pair_update<true><<<eg1, BLK, 0, stream>>>(psi, ei, ns, hsl + k*QD,
                                                       out, beta, E, invN);
    }
    // final node field from final psi -> marginal tail; psi (f32) already in d_out
    nodesumA<<<ng8, BLK, 0, stream>>>(psi, adj, rowstart, ns, hsl + 10*QD, beta, N);
    marginal_kernel<<<ng, BLK, 0, stream>>>(ns, out + (size_t)twoE*QD, N);
}

// Round 8
// 2065.531 us; speedup vs baseline: 1.2356x; 1.0700x over previous
//
#include <hip/hip_runtime.h>

#define QD 8
#define BLK 256

typedef unsigned short u16;
typedef unsigned int   u32;

__device__ __forceinline__ float bf2f(u16 u) {
    return __uint_as_float(((u32)u) << 16);
}
__device__ __forceinline__ u16 f2bf(float f) {   // RNE; inputs are finite probabilities
    u32 x = __float_as_uint(f);
    return (u16)((x + 0x7FFFu + ((x >> 16) & 1u)) >> 16);
}

__device__ __forceinline__ void load8(const float* __restrict__ p, float v[QD]) {
    const float4* p4 = reinterpret_cast<const float4*>(p);
    float4 a = p4[0], b = p4[1];
    v[0]=a.x; v[1]=a.y; v[2]=a.z; v[3]=a.w;
    v[4]=b.x; v[5]=b.y; v[6]=b.z; v[7]=b.w;
}
__device__ __forceinline__ void store8(float* __restrict__ p, const float v[QD]) {
    float4* p4 = reinterpret_cast<float4*>(p);
    float4 a = {v[0],v[1],v[2],v[3]};
    float4 b = {v[4],v[5],v[6],v[7]};
    p4[0]=a; p4[1]=b;
}
__device__ __forceinline__ void loadbf8(const u16* __restrict__ p, float v[QD]) {
    uint4 u = *reinterpret_cast<const uint4*>(p);
    v[0]=bf2f(u.x & 0xffff); v[1]=bf2f(u.x >> 16);
    v[2]=bf2f(u.y & 0xffff); v[3]=bf2f(u.y >> 16);
    v[4]=bf2f(u.z & 0xffff); v[5]=bf2f(u.z >> 16);
    v[6]=bf2f(u.w & 0xffff); v[7]=bf2f(u.w >> 16);
}
__device__ __forceinline__ void storebf8(u16* __restrict__ p, const float v[QD]) {
    uint4 u;
    u.x = (u32)f2bf(v[0]) | ((u32)f2bf(v[1]) << 16);
    u.y = (u32)f2bf(v[2]) | ((u32)f2bf(v[3]) << 16);
    u.z = (u32)f2bf(v[4]) | ((u32)f2bf(v[5]) << 16);
    u.w = (u32)f2bf(v[6]) | ((u32)f2bf(v[7]) << 16);
    *reinterpret_cast<uint4*>(p) = u;
}

__device__ __forceinline__ void softmax8(const float v[QD], float o[QD]) {
    float m = v[0];
    #pragma unroll
    for (int i=1;i<QD;i++) m = fmaxf(m, v[i]);
    float s = 0.f;
    #pragma unroll
    for (int i=0;i<QD;i++){ o[i] = expf(v[i]-m); s += o[i]; }
    float inv = 1.0f/s;
    #pragma unroll
    for (int i=0;i<QD;i++) o[i] *= inv;
}

// deg[ei[x]]++ over flat (2,E): multiset of dst over all directed edges == all ei entries
__global__ void count_kernel(const int* __restrict__ ei, int* __restrict__ deg, int twoE) {
    int x = blockIdx.x*BLK + threadIdx.x;
    if (x >= twoE) return;
    atomicAdd(&deg[ei[x]], 1);
}

// single-block exclusive scan: deg -> rowstart (N+1), cursor = rowstart
__global__ void scan_kernel(const int* __restrict__ deg, int* __restrict__ rowstart,
                            int* __restrict__ cursor, int N, int twoE) {
    __shared__ int part[1024];
    int tid = threadIdx.x;
    int chunk = (N + 1023) / 1024;
    int lo = tid * chunk;
    int hi = lo + chunk; if (hi > N) hi = N; if (lo > N) lo = N;
    int s = 0;
    for (int i = lo; i < hi; ++i) s += deg[i];
    part[tid] = s;
    __syncthreads();
    for (int off = 1; off < 1024; off <<= 1) {
        int v = (tid >= off) ? part[tid - off] : 0;
        __syncthreads();
        part[tid] += v;
        __syncthreads();
    }
    int run = (tid == 0) ? 0 : part[tid - 1];
    for (int i = lo; i < hi; ++i) {
        rowstart[i] = run; cursor[i] = run; run += deg[i];
    }
    if (tid == 1023) rowstart[N] = twoE;
}

// adj[slot] = e, slot grouped by dst[e] = ei[rev(e)]
__global__ void fill_kernel(const int* __restrict__ ei, int* __restrict__ cursor,
                            int* __restrict__ adj, int E, int twoE) {
    int e = blockIdx.x*BLK + threadIdx.x;
    if (e >= twoE) return;
    int r = (e < E) ? (e + E) : (e - E);
    int d = ei[r];
    int slot = atomicAdd(&cursor[d], 1);
    adj[slot] = e;
}

// psi_bf[e] = bf16(softmax(psi0[e])), contiguous
__global__ void init_kernel(const float* __restrict__ psi0, u16* __restrict__ psi, int twoE) {
    int e = blockIdx.x*BLK + threadIdx.x;
    if (e >= twoE) return;
    float v[QD], o[QD];
    load8(psi0 + (size_t)e*QD, v);
    softmax8(v, o);
    storebf8(psi + (size_t)e*QD, o);
}

// 8 lanes per node: ns[n][q] = sum over incoming edges of log1p(w*psi[adj[i]][q]).
// Gather loop unrolled x8: all adj loads issued, then all psi-row loads, then math —
// 8 lines in flight per node-group (latency hiding for the random gather).
// Fused h: 8-lane softmax -> marginal; wave-reduce same-q lanes -> 8 atomics/wave.
// FINAL: write softmax(ns) (the marginal) to marg instead of ns/h.
template<bool FINAL>
__global__ void nodesumA(const u16* __restrict__ psi, const int* __restrict__ adj,
                         const int* __restrict__ rowstart,
                         float* __restrict__ ns, float* __restrict__ hslot,
                         float* __restrict__ marg,
                         const float* __restrict__ beta, int N) {
    int gid = blockIdx.x*BLK + threadIdx.x;
    int node = gid >> 3;
    int q = gid & 7;
    float w = expf(beta[0]) - 1.0f;
    float hc = 0.0f;
    if (node < N) {
        int s = rowstart[node], t = rowstart[node + 1];
        float acc = 0.0f;
        int i = s;
        for (; i + 8 <= t; i += 8) {
            int e[8];
            #pragma unroll
            for (int k = 0; k < 8; ++k) e[k] = adj[i + k];
            u16 a[8];
            #pragma unroll
            for (int k = 0; k < 8; ++k) a[k] = psi[(size_t)e[k]*QD + q];
            #pragma unroll
            for (int k = 0; k < 8; ++k) acc += log1pf(w * bf2f(a[k]));
        }
        for (; i + 4 <= t; i += 4) {
            int e[4];
            #pragma unroll
            for (int k = 0; k < 4; ++k) e[k] = adj[i + k];
            u16 a[4];
            #pragma unroll
            for (int k = 0; k < 4; ++k) a[k] = psi[(size_t)e[k]*QD + q];
            #pragma unroll
            for (int k = 0; k < 4; ++k) acc += log1pf(w * bf2f(a[k]));
        }
        for (; i < t; ++i)
            acc += log1pf(w * bf2f(psi[(size_t)adj[i]*QD + q]));

        // softmax across the 8 lanes of this node-group
        float m = acc;
        #pragma unroll
        for (int d = 1; d < 8; d <<= 1) m = fmaxf(m, __shfl_xor(m, d, 8));
        float ex = expf(acc - m);
        float ss = ex;
        #pragma unroll
        for (int d = 1; d < 8; d <<= 1) ss += __shfl_xor(ss, d, 8);
        if (FINAL) {
            marg[(size_t)node*QD + q] = ex / ss;   // marginal, coalesced
        } else {
            ns[(size_t)node*QD + q] = acc;
            hc = ex / ss;                           // marginal[node][q] for h
        }
    }
    if (!FINAL) {
        hc += __shfl_xor(hc, 8);
        hc += __shfl_xor(hc, 16);
        hc += __shfl_xor(hc, 32);
        if ((threadIdx.x & 63) < 8) unsafeAtomicAdd(&hslot[threadIdx.x & 7], hc);
    }
}

// In-place pair update in EDGE space: edges t and t+E are mutual reverses.
// Thread t reads both rows contiguously, gathers ns (L2-resident), writes both in place.
//   psi[t]   = softmax( ns[ei[t]]   - log1p(w*psi[t+E]) - h )
//   psi[t+E] = softmax( ns[ei[t+E]] - log1p(w*psi[t])   - h )
// LAST: also write f32 rows to d_out (contiguous — edge order IS output order).
template<bool LAST>
__global__ void pair_update(u16* __restrict__ psi, const int* __restrict__ ei,
                            const float* __restrict__ ns, const float* __restrict__ hslot,
                            float* __restrict__ out, const float* __restrict__ beta,
                            int E, float invN) {
    int t = blockIdx.x*BLK + threadIdx.x;
    if (t >= E) return;
    float b = beta[0];
    float w = expf(b) - 1.0f;
    float hb = b * invN;
    int u = ei[t];          // src of edge t == dst of edge t+E
    int v = ei[t + E];      // dst of edge t == src of edge t+E
    float pf[QD], pr[QD], nsu[QD], nsv[QD], lg[QD], of_[QD], or_[QD], h8[QD];
    loadbf8(psi + (size_t)t*QD, pf);
    loadbf8(psi + ((size_t)t + E)*QD, pr);
    load8(ns + (size_t)u*QD, nsu);
    load8(ns + (size_t)v*QD, nsv);
    #pragma unroll
    for (int q = 0; q < QD; q++) h8[q] = hb * hslot[q];
    #pragma unroll
    for (int q = 0; q < QD; q++) lg[q] = nsu[q] - log1pf(w*pr[q]) - h8[q];
    softmax8(lg, of_);
    #pragma unroll
    for (int q = 0; q < QD; q++) lg[q] = nsv[q] - log1pf(w*pf[q]) - h8[q];
    softmax8(lg, or_);
    storebf8(psi + (size_t)t*QD, of_);
    storebf8(psi + ((size_t)t + E)*QD, or_);
    if (LAST) {
        store8(out + (size_t)t*QD, of_);
        store8(out + ((size_t)t + E)*QD, or_);
    }
}

extern "C" void kernel_launch(void* const* d_in, const int* in_sizes, int n_in,
                              void* d_out, int out_size, void* d_ws, size_t ws_size,
                              hipStream_t stream) {
    const int*   ei   = (const int*)d_in[0];    // (2,E) flat: [0..E)=src_u, [E..2E)=dst_u
    const float* psi0 = (const float*)d_in[1];  // (2E, Q)
    const float* beta = (const float*)d_in[2];  // (1,)

    int twoE = in_sizes[0];
    int E    = twoE / 2;
    int N    = (out_size - in_sizes[1]) / QD;

    // workspace layout (256B-aligned); total ~34.3 MB
    char* w = (char*)d_ws;
    size_t o = 0;
    auto al = [](size_t x){ return (x + 255) & ~(size_t)255; };
    u16*  psi    = (u16*)(w + o);   o = al(o + (size_t)twoE*QD*2);  // 25.6 MB
    int*  adj    = (int*)(w + o);   o = al(o + (size_t)twoE*4);     //  6.4 MB
    float* ns    = (float*)(w + o); o = al(o + (size_t)N*QD*4);     //  1.6 MB
    int*  deg    = (int*)(w + o);   o = al(o + (size_t)N*4);
    int*  rowstart=(int*)(w + o);   o = al(o + ((size_t)N+1)*4);
    int*  cursor = (int*)(w + o);   o = al(o + (size_t)N*4);
    float* hsl   = (float*)(w + o);                                  // 11*8 floats

    int eg2 = (twoE + BLK - 1) / BLK;
    int eg1 = (E    + BLK - 1) / BLK;
    int ng8 = (N*QD + BLK - 1) / BLK;
    float invN = 1.0f / (float)N;
    float* out = (float*)d_out;

    hipMemsetAsync(deg, 0, (size_t)N * sizeof(int), stream);
    hipMemsetAsync(hsl, 0, (size_t)11 * QD * sizeof(float), stream);

    count_kernel<<<eg2, BLK, 0, stream>>>(ei, deg, twoE);
    scan_kernel<<<1, 1024, 0, stream>>>(deg, rowstart, cursor, N, twoE);
    fill_kernel<<<eg2, BLK, 0, stream>>>(ei, cursor, adj, E, twoE);
    init_kernel<<<eg2, BLK, 0, stream>>>(psi0, psi, twoE);

    for (int k = 0; k < 10; ++k) {
        nodesumA<false><<<ng8, BLK, 0, stream>>>(psi, adj, rowstart, ns, hsl + k*QD,
                                                 nullptr, beta, N);
        if (k < 9)
            pair_update<false><<<eg1, BLK, 0, stream>>>(psi, ei, ns, hsl + k*QD,
                                                        out, beta, E, invN);
        else
            pair_update<true><<<eg1, BLK, 0, stream>>>(psi, ei, ns, hsl + k*QD,
                                                       out, beta, E, invN);
    }
    // final node field fused with marginal: writes softmax(ns) straight to out tail
    nodesumA<true><<<ng8, BLK, 0, stream>>>(psi, adj, rowstart, ns, hsl + 10*QD,
                                            out + (size_t)twoE*QD, beta, N);
}

// Round 11
// 1697.870 us; speedup vs baseline: 1.5032x; 1.2165x over previous
//
#include <hip/hip_runtime.h>

#define QD 8
#define BLK 256
#define NBIN 1024

typedef unsigned short u16;
typedef unsigned int   u32;

__device__ __forceinline__ float bf2f(u16 u) {
    return __uint_as_float(((u32)u) << 16);
}
__device__ __forceinline__ u16 f2bf(float f) {   // RNE; inputs are finite probabilities
    u32 x = __float_as_uint(f);
    return (u16)((x + 0x7FFFu + ((x >> 16) & 1u)) >> 16);
}

__device__ __forceinline__ void load8(const float* __restrict__ p, float v[QD]) {
    const float4* p4 = reinterpret_cast<const float4*>(p);
    float4 a = p4[0], b = p4[1];
    v[0]=a.x; v[1]=a.y; v[2]=a.z; v[3]=a.w;
    v[4]=b.x; v[5]=b.y; v[6]=b.z; v[7]=b.w;
}
__device__ __forceinline__ void store8(float* __restrict__ p, const float v[QD]) {
    float4* p4 = reinterpret_cast<float4*>(p);
    float4 a = {v[0],v[1],v[2],v[3]};
    float4 b = {v[4],v[5],v[6],v[7]};
    p4[0]=a; p4[1]=b;
}
__device__ __forceinline__ void loadbf8(const u16* __restrict__ p, float v[QD]) {
    uint4 u = *reinterpret_cast<const uint4*>(p);
    v[0]=bf2f(u.x & 0xffff); v[1]=bf2f(u.x >> 16);
    v[2]=bf2f(u.y & 0xffff); v[3]=bf2f(u.y >> 16);
    v[4]=bf2f(u.z & 0xffff); v[5]=bf2f(u.z >> 16);
    v[6]=bf2f(u.w & 0xffff); v[7]=bf2f(u.w >> 16);
}
__device__ __forceinline__ void storebf8(u16* __restrict__ p, const float v[QD]) {
    uint4 u;
    u.x = (u32)f2bf(v[0]) | ((u32)f2bf(v[1]) << 16);
    u.y = (u32)f2bf(v[2]) | ((u32)f2bf(v[3]) << 16);
    u.z = (u32)f2bf(v[4]) | ((u32)f2bf(v[5]) << 16);
    u.w = (u32)f2bf(v[6]) | ((u32)f2bf(v[7]) << 16);
    *reinterpret_cast<uint4*>(p) = u;
}

// fast softmax: v_exp_f32 path; inputs are well-bounded logits
__device__ __forceinline__ void softmax8(const float v[QD], float o[QD]) {
    float m = v[0];
    #pragma unroll
    for (int i=1;i<QD;i++) m = fmaxf(m, v[i]);
    float s = 0.f;
    #pragma unroll
    for (int i=0;i<QD;i++){ o[i] = __expf(v[i]-m); s += o[i]; }
    float inv = 1.0f/s;
    #pragma unroll
    for (int i=0;i<QD;i++) o[i] *= inv;
}

// deg[ei[x]]++ over flat (2,E): multiset of dst over all directed edges == all ei entries
__global__ void count_kernel(const int* __restrict__ ei, int* __restrict__ deg, int twoE) {
    int x = blockIdx.x*BLK + threadIdx.x;
    if (x >= twoE) return;
    atomicAdd(&deg[ei[x]], 1);
}

// single-block exclusive scan: deg -> rowstart (N+1), cursor = rowstart
__global__ void scan_kernel(const int* __restrict__ deg, int* __restrict__ rowstart,
                            int* __restrict__ cursor, int N, int twoE) {
    __shared__ int part[1024];
    int tid = threadIdx.x;
    int chunk = (N + 1023) / 1024;
    int lo = tid * chunk;
    int hi = lo + chunk; if (hi > N) hi = N; if (lo > N) lo = N;
    int s = 0;
    for (int i = lo; i < hi; ++i) s += deg[i];
    part[tid] = s;
    __syncthreads();
    for (int off = 1; off < 1024; off <<= 1) {
        int v = (tid >= off) ? part[tid - off] : 0;
        __syncthreads();
        part[tid] += v;
        __syncthreads();
    }
    int run = (tid == 0) ? 0 : part[tid - 1];
    for (int i = lo; i < hi; ++i) {
        rowstart[i] = run; cursor[i] = run; run += deg[i];
    }
    if (tid == 1023) rowstart[N] = twoE;
}

// degree histogram (capped at NBIN-1)
__global__ void histo_kernel(const int* __restrict__ deg, int* __restrict__ histo, int N) {
    int n = blockIdx.x*BLK + threadIdx.x;
    if (n >= N) return;
    int b = deg[n]; if (b > NBIN-1) b = NBIN-1;
    atomicAdd(&histo[b], 1);
}

// single-block exclusive scan of histo -> hcur (bin cursors)
__global__ void hscan_kernel(const int* __restrict__ histo, int* __restrict__ hcur) {
    __shared__ int part[NBIN];
    int tid = threadIdx.x;
    part[tid] = histo[tid];
    __syncthreads();
    for (int off = 1; off < NBIN; off <<= 1) {
        int v = (tid >= off) ? part[tid - off] : 0;
        __syncthreads();
        part[tid] += v;
        __syncthreads();
    }
    hcur[tid] = (tid == 0) ? 0 : part[tid - 1];
}

// order: nodes grouped by degree (uniform trip counts within a wave)
__global__ void order_kernel(const int* __restrict__ deg, int* __restrict__ hcur,
                             int* __restrict__ order, int N) {
    int n = blockIdx.x*BLK + threadIdx.x;
    if (n >= N) return;
    int b = deg[n]; if (b > NBIN-1) b = NBIN-1;
    int pos = atomicAdd(&hcur[b], 1);
    order[pos] = n;
}

// adj[slot] = e (slot grouped by dst[e]); fused psi init: psi[e] = bf16(softmax(psi0[e]))
__global__ void fill_kernel(const int* __restrict__ ei, const float* __restrict__ psi0,
                            int* __restrict__ cursor, int* __restrict__ adj,
                            u16* __restrict__ psi, int E, int twoE) {
    int e = blockIdx.x*BLK + threadIdx.x;
    if (e >= twoE) return;
    int r = (e < E) ? (e + E) : (e - E);
    int d = ei[r];
    int slot = atomicAdd(&cursor[d], 1);
    adj[slot] = e;
    float v[QD], o[QD];
    load8(psi0 + (size_t)e*QD, v);
    softmax8(v, o);
    storebf8(psi + (size_t)e*QD, o);
}

// 8 lanes per node (node = order[group]: degree-sorted -> uniform waves).
// ns[n][q] = sum log1p(w*psi[adj[i]][q]) over the node's incoming slots; 16-deep batches.
// Fused h: 8-lane softmax -> marginal; wave-reduce same-q lanes -> 8 atomics/wave.
// FINAL: write softmax(ns) (the marginal) to marg instead of ns/h.
template<bool FINAL>
__global__ void nodesumA(const u16* __restrict__ psi, const int* __restrict__ adj,
                         const int* __restrict__ rowstart, const int* __restrict__ order,
                         float* __restrict__ ns, float* __restrict__ hslot,
                         float* __restrict__ marg,
                         const float* __restrict__ beta, int N) {
    int gid = blockIdx.x*BLK + threadIdx.x;
    int g = gid >> 3;
    int q = gid & 7;
    float w = __expf(beta[0]) - 1.0f;
    float hc = 0.0f;
    if (g < N) {
        int node = order[g];
        int s = rowstart[node], t = rowstart[node + 1];
        float acc = 0.0f;
        int i = s;
        for (; i + 16 <= t; i += 16) {
            int e[16];
            #pragma unroll
            for (int k = 0; k < 16; ++k) e[k] = adj[i + k];
            u16 a[16];
            #pragma unroll
            for (int k = 0; k < 16; ++k) a[k] = psi[(size_t)e[k]*QD + q];
            #pragma unroll
            for (int k = 0; k < 16; ++k) acc += __logf(fmaf(w, bf2f(a[k]), 1.0f));
        }
        for (; i + 4 <= t; i += 4) {
            int e[4];
            #pragma unroll
            for (int k = 0; k < 4; ++k) e[k] = adj[i + k];
            u16 a[4];
            #pragma unroll
            for (int k = 0; k < 4; ++k) a[k] = psi[(size_t)e[k]*QD + q];
            #pragma unroll
            for (int k = 0; k < 4; ++k) acc += __logf(fmaf(w, bf2f(a[k]), 1.0f));
        }
        for (; i < t; ++i)
            acc += __logf(fmaf(w, bf2f(psi[(size_t)adj[i]*QD + q]), 1.0f));

        // softmax across the 8 lanes of this node-group
        float m = acc;
        #pragma unroll
        for (int d = 1; d < 8; d <<= 1) m = fmaxf(m, __shfl_xor(m, d, 8));
        float ex = __expf(acc - m);
        float ss = ex;
        #pragma unroll
        for (int d = 1; d < 8; d <<= 1) ss += __shfl_xor(ss, d, 8);
        if (FINAL) {
            marg[(size_t)node*QD + q] = ex / ss;   // marginal
        } else {
            ns[(size_t)node*QD + q] = acc;
            hc = ex / ss;                           // marginal[node][q] for h
        }
    }
    if (!FINAL) {
        hc += __shfl_xor(hc, 8);
        hc += __shfl_xor(hc, 16);
        hc += __shfl_xor(hc, 32);
        if ((threadIdx.x & 63) < 8) unsafeAtomicAdd(&hslot[threadIdx.x & 7], hc);
    }
}

// In-place pair update in EDGE space: edges t and t+E are mutual reverses.
// Thread t reads both rows contiguously, gathers ns (L2-resident), writes both in place.
//   psi[t]   = softmax( ns[ei[t]]   - log1p(w*psi[t+E]) - h )
//   psi[t+E] = softmax( ns[ei[t+E]] - log1p(w*psi[t])   - h )
// LAST: also write f32 rows to d_out (contiguous — edge order IS output order).
template<bool LAST>
__global__ void pair_update(u16* __restrict__ psi, const int* __restrict__ ei,
                            const float* __restrict__ ns, const float* __restrict__ hslot,
                            float* __restrict__ out, const float* __restrict__ beta,
                            int E, float invN) {
    int t = blockIdx.x*BLK + threadIdx.x;
    if (t >= E) return;
    float b = beta[0];
    float w = __expf(b) - 1.0f;
    float hb = b * invN;
    int u = ei[t];          // src of edge t == dst of edge t+E
    int v = ei[t + E];      // dst of edge t == src of edge t+E
    float pf[QD], pr[QD], nsu[QD], nsv[QD], lg[QD], of_[QD], or_[QD], h8[QD];
    loadbf8(psi + (size_t)t*QD, pf);
    loadbf8(psi + ((size_t)t + E)*QD, pr);
    load8(ns + (size_t)u*QD, nsu);
    load8(ns + (size_t)v*QD, nsv);
    #pragma unroll
    for (int q = 0; q < QD; q++) h8[q] = hb * hslot[q];
    #pragma unroll
    for (int q = 0; q < QD; q++) lg[q] = nsu[q] - __logf(fmaf(w, pr[q], 1.0f)) - h8[q];
    softmax8(lg, of_);
    #pragma unroll
    for (int q = 0; q < QD; q++) lg[q] = nsv[q] - __logf(fmaf(w, pf[q], 1.0f)) - h8[q];
    softmax8(lg, or_);
    storebf8(psi + (size_t)t*QD, of_);
    storebf8(psi + ((size_t)t + E)*QD, or_);
    if (LAST) {
        store8(out + (size_t)t*QD, of_);
        store8(out + ((size_t)t + E)*QD, or_);
    }
}

extern "C" void kernel_launch(void* const* d_in, const int* in_sizes, int n_in,
                              void* d_out, int out_size, void* d_ws, size_t ws_size,
                              hipStream_t stream) {
    const int*   ei   = (const int*)d_in[0];    // (2,E) flat: [0..E)=src_u, [E..2E)=dst_u
    const float* psi0 = (const float*)d_in[1];  // (2E, Q)
    const float* beta = (const float*)d_in[2];  // (1,)

    int twoE = in_sizes[0];
    int E    = twoE / 2;
    int N    = (out_size - in_sizes[1]) / QD;

    // workspace layout (256B-aligned); total ~34.6 MB
    char* w = (char*)d_ws;
    size_t o = 0;
    auto al = [](size_t x){ return (x + 255) & ~(size_t)255; };
    u16*  psi    = (u16*)(w + o);   o = al(o + (size_t)twoE*QD*2);  // 25.6 MB
    int*  adj    = (int*)(w + o);   o = al(o + (size_t)twoE*4);     //  6.4 MB
    float* ns    = (float*)(w + o); o = al(o + (size_t)N*QD*4);     //  1.6 MB
    int*  deg    = (int*)(w + o);   o = al(o + (size_t)N*4);
    int*  rowstart=(int*)(w + o);   o = al(o + ((size_t)N+1)*4);
    int*  cursor = (int*)(w + o);   o = al(o + (size_t)N*4);
    int*  order  = (int*)(w + o);   o = al(o + (size_t)N*4);
    int*  histo  = (int*)(w + o);   o = al(o + (size_t)NBIN*4);
    int*  hcur   = (int*)(w + o);   o = al(o + (size_t)NBIN*4);
    float* hsl   = (float*)(w + o);                                  // 11*8 floats

    int eg2 = (twoE + BLK - 1) / BLK;
    int eg1 = (E    + BLK - 1) / BLK;
    int ng8 = (N*QD + BLK - 1) / BLK;
    int ng  = (N    + BLK - 1) / BLK;
    float invN = 1.0f / (float)N;
    float* out = (float*)d_out;

    hipMemsetAsync(deg,   0, (size_t)N * sizeof(int), stream);
    hipMemsetAsync(histo, 0, (size_t)NBIN * sizeof(int), stream);
    hipMemsetAsync(hsl,   0, (size_t)11 * QD * sizeof(float), stream);

    count_kernel<<<eg2, BLK, 0, stream>>>(ei, deg, twoE);
    scan_kernel<<<1, 1024, 0, stream>>>(deg, rowstart, cursor, N, twoE);
    histo_kernel<<<ng, BLK, 0, stream>>>(deg, histo, N);
    hscan_kernel<<<1, NBIN, 0, stream>>>(histo, hcur);
    order_kernel<<<ng, BLK, 0, stream>>>(deg, hcur, order, N);
    fill_kernel<<<eg2, BLK, 0, stream>>>(ei, psi0, cursor, adj, psi, E, twoE);

    for (int k = 0; k < 10; ++k) {
        nodesumA<false><<<ng8, BLK, 0, stream>>>(psi, adj, rowstart, order, ns,
                                                 hsl + k*QD, nullptr, beta, N);
        if (k < 9)
            pair_update<false><<<eg1, BLK, 0, stream>>>(psi, ei, ns, hsl + k*QD,
                                                        out, beta, E, invN);
        else
            pair_update<true><<<eg1, BLK, 0, stream>>>(psi, ei, ns, hsl + k*QD,
                                                       out, beta, E, invN);
    }
    // final node field fused with marginal: writes softmax(ns) straight to out tail
    nodesumA<true><<<ng8, BLK, 0, stream>>>(psi, adj, rowstart, order, ns,
                                            hsl + 10*QD, out + (size_t)twoE*QD, beta, N);
}

// Round 12
// 1613.135 us; speedup vs baseline: 1.5821x; 1.0525x over previous
//
#include <hip/hip_runtime.h>

#define QD 8
#define BLK 256
#define NBIN 256

typedef unsigned short u16;
typedef unsigned int   u32;

__device__ __forceinline__ float bf2f(u16 u) {
    return __uint_as_float(((u32)u) << 16);
}
__device__ __forceinline__ u16 f2bf(float f) {   // RNE; inputs are finite probabilities
    u32 x = __float_as_uint(f);
    return (u16)((x + 0x7FFFu + ((x >> 16) & 1u)) >> 16);
}

__device__ __forceinline__ void load8(const float* __restrict__ p, float v[QD]) {
    const float4* p4 = reinterpret_cast<const float4*>(p);
    float4 a = p4[0], b = p4[1];
    v[0]=a.x; v[1]=a.y; v[2]=a.z; v[3]=a.w;
    v[4]=b.x; v[5]=b.y; v[6]=b.z; v[7]=b.w;
}
__device__ __forceinline__ void store8(float* __restrict__ p, const float v[QD]) {
    float4* p4 = reinterpret_cast<float4*>(p);
    float4 a = {v[0],v[1],v[2],v[3]};
    float4 b = {v[4],v[5],v[6],v[7]};
    p4[0]=a; p4[1]=b;
}
__device__ __forceinline__ void loadbf8(const u16* __restrict__ p, float v[QD]) {
    uint4 u = *reinterpret_cast<const uint4*>(p);
    v[0]=bf2f(u.x & 0xffff); v[1]=bf2f(u.x >> 16);
    v[2]=bf2f(u.y & 0xffff); v[3]=bf2f(u.y >> 16);
    v[4]=bf2f(u.z & 0xffff); v[5]=bf2f(u.z >> 16);
    v[6]=bf2f(u.w & 0xffff); v[7]=bf2f(u.w >> 16);
}
__device__ __forceinline__ void storebf8(u16* __restrict__ p, const float v[QD]) {
    uint4 u;
    u.x = (u32)f2bf(v[0]) | ((u32)f2bf(v[1]) << 16);
    u.y = (u32)f2bf(v[2]) | ((u32)f2bf(v[3]) << 16);
    u.z = (u32)f2bf(v[4]) | ((u32)f2bf(v[5]) << 16);
    u.w = (u32)f2bf(v[6]) | ((u32)f2bf(v[7]) << 16);
    *reinterpret_cast<uint4*>(p) = u;
}

// fast softmax: v_exp_f32 path; inputs are well-bounded logits
__device__ __forceinline__ void softmax8(const float v[QD], float o[QD]) {
    float m = v[0];
    #pragma unroll
    for (int i=1;i<QD;i++) m = fmaxf(m, v[i]);
    float s = 0.f;
    #pragma unroll
    for (int i=0;i<QD;i++){ o[i] = __expf(v[i]-m); s += o[i]; }
    float inv = 1.0f/s;
    #pragma unroll
    for (int i=0;i<QD;i++) o[i] *= inv;
}

// deg[ei[x]]++ over flat (2,E): multiset of dst over all directed edges == all ei entries
__global__ void count_kernel(const int* __restrict__ ei, int* __restrict__ deg, int twoE) {
    int x = blockIdx.x*BLK + threadIdx.x;
    if (x >= twoE) return;
    atomicAdd(&deg[ei[x]], 1);
}

// two-level parallel exclusive scan of deg -> rowstart/cursor
// scan1: per-block LDS exclusive scan; local prefix -> cursor (temp), block sum -> bsum
__global__ void scan1_kernel(const int* __restrict__ deg, int* __restrict__ local,
                             int* __restrict__ bsum, int N) {
    __shared__ int sh[BLK];
    int n = blockIdx.x*BLK + threadIdx.x;
    int v = (n < N) ? deg[n] : 0;
    sh[threadIdx.x] = v;
    __syncthreads();
    #pragma unroll
    for (int off = 1; off < BLK; off <<= 1) {
        int t = (threadIdx.x >= off) ? sh[threadIdx.x - off] : 0;
        __syncthreads();
        sh[threadIdx.x] += t;
        __syncthreads();
    }
    if (n < N) local[n] = sh[threadIdx.x] - v;          // exclusive local prefix
    if (threadIdx.x == BLK-1) bsum[blockIdx.x] = sh[BLK-1];
}

// scan2: single block scans the (<=1024) block sums to exclusive offsets
__global__ void scan2_kernel(int* __restrict__ bsum, int nb) {
    __shared__ int sh[1024];
    int t = threadIdx.x;
    int v = (t < nb) ? bsum[t] : 0;
    sh[t] = v;
    __syncthreads();
    for (int off = 1; off < 1024; off <<= 1) {
        int x = (t >= off) ? sh[t - off] : 0;
        __syncthreads();
        sh[t] += x;
        __syncthreads();
    }
    if (t < nb) bsum[t] = sh[t] - v;                    // exclusive block offset
}

// scan3: add block offsets; write rowstart and cursor
__global__ void scan3_kernel(const int* __restrict__ bsum, int* __restrict__ local_cursor,
                             int* __restrict__ rowstart, int N, int twoE) {
    int n = blockIdx.x*BLK + threadIdx.x;
    if (n < N) {
        int r = local_cursor[n] + bsum[blockIdx.x];
        rowstart[n] = r;
        local_cursor[n] = r;                            // cursor = rowstart
    }
    if (n == 0) rowstart[N] = twoE;
}

// degree histogram (capped at NBIN-1)
__global__ void histo_kernel(const int* __restrict__ deg, int* __restrict__ histo, int N) {
    int n = blockIdx.x*BLK + threadIdx.x;
    if (n >= N) return;
    int b = deg[n]; if (b > NBIN-1) b = NBIN-1;
    atomicAdd(&histo[b], 1);
}

// single-block exclusive scan of histo -> hcur (bin cursors)
__global__ void hscan_kernel(const int* __restrict__ histo, int* __restrict__ hcur) {
    __shared__ int part[NBIN];
    int tid = threadIdx.x;
    part[tid] = histo[tid];
    __syncthreads();
    for (int off = 1; off < NBIN; off <<= 1) {
        int v = (tid >= off) ? part[tid - off] : 0;
        __syncthreads();
        part[tid] += v;
        __syncthreads();
    }
    hcur[tid] = (tid == 0) ? 0 : part[tid - 1];
}

// order: nodes grouped by degree (uniform trip counts within a wave)
__global__ void order_kernel(const int* __restrict__ deg, int* __restrict__ hcur,
                             int* __restrict__ order, int N) {
    int n = blockIdx.x*BLK + threadIdx.x;
    if (n >= N) return;
    int b = deg[n]; if (b > NBIN-1) b = NBIN-1;
    int pos = atomicAdd(&hcur[b], 1);
    order[pos] = n;
}

// adj[slot] = e (slot grouped by dst[e]); fused psi init: psi[e] = bf16(softmax(psi0[e]))
__global__ void fill_kernel(const int* __restrict__ ei, const float* __restrict__ psi0,
                            int* __restrict__ cursor, int* __restrict__ adj,
                            u16* __restrict__ psi, int E, int twoE) {
    int e = blockIdx.x*BLK + threadIdx.x;
    if (e >= twoE) return;
    int r = (e < E) ? (e + E) : (e - E);
    int d = ei[r];
    int slot = atomicAdd(&cursor[d], 1);
    adj[slot] = e;
    float v[QD], o[QD];
    load8(psi0 + (size_t)e*QD, v);
    softmax8(v, o);
    storebf8(psi + (size_t)e*QD, o);
}

// 8 lanes per node (node = order[group]: degree-sorted -> uniform waves).
// ns[n][q] = sum log1p(w*psi[adj[i]][q]) over the node's incoming slots; 16-deep batches.
// Fused h: 8-lane softmax -> marginal; wave-reduce same-q lanes -> 8 atomics/wave.
// FINAL: write softmax(ns) (the marginal) to marg instead of ns/h.
template<bool FINAL>
__global__ void nodesumA(const u16* __restrict__ psi, const int* __restrict__ adj,
                         const int* __restrict__ rowstart, const int* __restrict__ order,
                         float* __restrict__ ns, float* __restrict__ hslot,
                         float* __restrict__ marg,
                         const float* __restrict__ beta, int N) {
    int gid = blockIdx.x*BLK + threadIdx.x;
    int g = gid >> 3;
    int q = gid & 7;
    float w = __expf(beta[0]) - 1.0f;
    float hc = 0.0f;
    if (g < N) {
        int node = order[g];
        int s = rowstart[node], t = rowstart[node + 1];
        float acc = 0.0f;
        int i = s;
        for (; i + 16 <= t; i += 16) {
            int e[16];
            #pragma unroll
            for (int k = 0; k < 16; ++k) e[k] = adj[i + k];
            u16 a[16];
            #pragma unroll
            for (int k = 0; k < 16; ++k) a[k] = psi[(size_t)((u32)e[k]*QD + q)];
            #pragma unroll
            for (int k = 0; k < 16; ++k) acc += __logf(fmaf(w, bf2f(a[k]), 1.0f));
        }
        for (; i + 4 <= t; i += 4) {
            int e[4];
            #pragma unroll
            for (int k = 0; k < 4; ++k) e[k] = adj[i + k];
            u16 a[4];
            #pragma unroll
            for (int k = 0; k < 4; ++k) a[k] = psi[(size_t)((u32)e[k]*QD + q)];
            #pragma unroll
            for (int k = 0; k < 4; ++k) acc += __logf(fmaf(w, bf2f(a[k]), 1.0f));
        }
        for (; i < t; ++i)
            acc += __logf(fmaf(w, bf2f(psi[(size_t)((u32)adj[i]*QD + q)]), 1.0f));

        // softmax across the 8 lanes of this node-group
        float m = acc;
        #pragma unroll
        for (int d = 1; d < 8; d <<= 1) m = fmaxf(m, __shfl_xor(m, d, 8));
        float ex = __expf(acc - m);
        float ss = ex;
        #pragma unroll
        for (int d = 1; d < 8; d <<= 1) ss += __shfl_xor(ss, d, 8);
        if (FINAL) {
            marg[(size_t)node*QD + q] = ex / ss;   // marginal
        } else {
            ns[(size_t)node*QD + q] = acc;
            hc = ex / ss;                           // marginal[node][q] for h
        }
    }
    if (!FINAL) {
        hc += __shfl_xor(hc, 8);
        hc += __shfl_xor(hc, 16);
        hc += __shfl_xor(hc, 32);
        if ((threadIdx.x & 63) < 8) unsafeAtomicAdd(&hslot[threadIdx.x & 7], hc);
    }
}

// In-place pair update in EDGE space: edges t and t+E are mutual reverses.
// Thread t reads both rows contiguously, gathers ns (L2-resident), writes both in place.
//   psi[t]   = softmax( ns[ei[t]]   - log1p(w*psi[t+E]) - h )
//   psi[t+E] = softmax( ns[ei[t+E]] - log1p(w*psi[t])   - h )
// LAST: also write f32 rows to d_out (contiguous — edge order IS output order).
template<bool LAST>
__global__ void pair_update(u16* __restrict__ psi, const int* __restrict__ ei,
                            const float* __restrict__ ns, const float* __restrict__ hslot,
                            float* __restrict__ out, const float* __restrict__ beta,
                            int E, float invN) {
    int t = blockIdx.x*BLK + threadIdx.x;
    if (t >= E) return;
    float b = beta[0];
    float w = __expf(b) - 1.0f;
    float hb = b * invN;
    int u = ei[t];          // src of edge t == dst of edge t+E
    int v = ei[t + E];      // dst of edge t == src of edge t+E
    float pf[QD], pr[QD], nsu[QD], nsv[QD], lg[QD], of_[QD], or_[QD], h8[QD];
    loadbf8(psi + (size_t)t*QD, pf);
    loadbf8(psi + ((size_t)t + E)*QD, pr);
    load8(ns + (size_t)u*QD, nsu);
    load8(ns + (size_t)v*QD, nsv);
    #pragma unroll
    for (int q = 0; q < QD; q++) h8[q] = hb * hslot[q];
    #pragma unroll
    for (int q = 0; q < QD; q++) lg[q] = nsu[q] - __logf(fmaf(w, pr[q], 1.0f)) - h8[q];
    softmax8(lg, of_);
    #pragma unroll
    for (int q = 0; q < QD; q++) lg[q] = nsv[q] - __logf(fmaf(w, pf[q], 1.0f)) - h8[q];
    softmax8(lg, or_);
    storebf8(psi + (size_t)t*QD, of_);
    storebf8(psi + ((size_t)t + E)*QD, or_);
    if (LAST) {
        store8(out + (size_t)t*QD, of_);
        store8(out + ((size_t)t + E)*QD, or_);
    }
}

extern "C" void kernel_launch(void* const* d_in, const int* in_sizes, int n_in,
                              void* d_out, int out_size, void* d_ws, size_t ws_size,
                              hipStream_t stream) {
    const int*   ei   = (const int*)d_in[0];    // (2,E) flat: [0..E)=src_u, [E..2E)=dst_u
    const float* psi0 = (const float*)d_in[1];  // (2E, Q)
    const float* beta = (const float*)d_in[2];  // (1,)

    int twoE = in_sizes[0];
    int E    = twoE / 2;
    int N    = (out_size - in_sizes[1]) / QD;

    // workspace layout (256B-aligned); total ~34.6 MB
    char* w = (char*)d_ws;
    size_t o = 0;
    auto al = [](size_t x){ return (x + 255) & ~(size_t)255; };
    u16*  psi    = (u16*)(w + o);   o = al(o + (size_t)twoE*QD*2);  // 25.6 MB
    int*  adj    = (int*)(w + o);   o = al(o + (size_t)twoE*4);     //  6.4 MB
    float* ns    = (float*)(w + o); o = al(o + (size_t)N*QD*4);     //  1.6 MB
    int*  deg    = (int*)(w + o);   o = al(o + (size_t)N*4);
    int*  rowstart=(int*)(w + o);   o = al(o + ((size_t)N+1)*4);
    int*  cursor = (int*)(w + o);   o = al(o + (size_t)N*4);
    int*  order  = (int*)(w + o);   o = al(o + (size_t)N*4);
    int*  histo  = (int*)(w + o);   o = al(o + (size_t)NBIN*4);
    int*  hcur   = (int*)(w + o);   o = al(o + (size_t)NBIN*4);
    int*  bsum   = (int*)(w + o);   o = al(o + (size_t)1024*4);
    float* hsl   = (float*)(w + o);                                  // 11*8 floats

    int eg2 = (twoE + BLK - 1) / BLK;
    int eg1 = (E    + BLK - 1) / BLK;
    int ng8 = (N*QD + BLK - 1) / BLK;
    int ng  = (N    + BLK - 1) / BLK;   // also = #blocks in scan1/scan3 (<=1024 for N<=262144)
    float invN = 1.0f / (float)N;
    float* out = (float*)d_out;

    hipMemsetAsync(deg,   0, (size_t)N * sizeof(int), stream);
    hipMemsetAsync(histo, 0, (size_t)NBIN * sizeof(int), stream);
    hipMemsetAsync(hsl,   0, (size_t)11 * QD * sizeof(float), stream);

    count_kernel<<<eg2, BLK, 0, stream>>>(ei, deg, twoE);
    scan1_kernel<<<ng, BLK, 0, stream>>>(deg, cursor, bsum, N);
    scan2_kernel<<<1, 1024, 0, stream>>>(bsum, ng);
    scan3_kernel<<<ng, BLK, 0, stream>>>(bsum, cursor, rowstart, N, twoE);
    histo_kernel<<<ng, BLK, 0, stream>>>(deg, histo, N);
    hscan_kernel<<<1, NBIN, 0, stream>>>(histo, hcur);
    order_kernel<<<ng, BLK, 0, stream>>>(deg, hcur, order, N);
    fill_kernel<<<eg2, BLK, 0, stream>>>(ei, psi0, cursor, adj, psi, E, twoE);

    for (int k = 0; k < 10; ++k) {
        nodesumA<false><<<ng8, BLK, 0, stream>>>(psi, adj, rowstart, order, ns,
                                                 hsl + k*QD, nullptr, beta, N);
        if (k < 9)
            pair_update<false><<<eg1, BLK, 0, stream>>>(psi, ei, ns, hsl + k*QD,
                                                        out, beta, E, invN);
        else
            pair_update<true><<<eg1, BLK, 0, stream>>>(psi, ei, ns, hsl + k*QD,
                                                       out, beta, E, invN);
    }
    // final node field fused with marginal: writes softmax(ns) straight to out tail
    nodesumA<true><<<ng8, BLK, 0, stream>>>(psi, adj, rowstart, order, ns,
                                            hsl + 10*QD, out + (size_t)twoE*QD, beta, N);
}